// Round 1
// baseline (642.104 us; speedup 1.0000x reference)
//
#include <hip/hip_runtime.h>

// Problem constants (fixed by setup_inputs: B=64, C=16, T=32768, fp32)
#define B_BATCH 64
#define C_CH    16
#define T_LEN   32768
#define THREADS 256
#define TPT     16                       // elements per thread (kept in registers)
#define TILE    (THREADS * TPT)          // 4096 elements per tile
#define GSEG    (T_LEN / TILE)           // 8 tiles per row
#define NROWS   (B_BATCH * C_CH)         // 1024 rows
#define NBLOCKS (NROWS * GSEG)           // 8192 blocks -> 32 blocks/CU of work

// d_ws layout (zeroed once per launch):
//   [0,8)              double accum
//   [8,12)             uint   ticket   (virtual block id, start-ordered)
//   [12,16)            uint   donecnt
//   [16,16+NBLOCKS*8)  u64 slot per tile: (flag<<32)|fp32bits; 0=empty,1=agg,2=inclusive
#define WS_BYTES (16 + NBLOCKS * 8)

__device__ __forceinline__ unsigned long long pack_slot(unsigned int flag, float v) {
    return ((unsigned long long)flag << 32) | (unsigned long long)__float_as_uint(v);
}

__global__ __launch_bounds__(THREADS) void wloss_lookback_kernel(
    const float* __restrict__ pred,
    const float* __restrict__ tru,
    void* __restrict__ ws,
    float* __restrict__ out)
{
    double*             accum   = (double*)ws;
    unsigned int*       ticket  = (unsigned int*)((char*)ws + 8);
    unsigned int*       donecnt = (unsigned int*)((char*)ws + 12);
    unsigned long long* slots   = (unsigned long long*)((char*)ws + 16);

    __shared__ unsigned int s_bid;
    __shared__ float  s_wtot[4];
    __shared__ float  s_carry;
    __shared__ double s_dtot[4];

    const int tid  = threadIdx.x;
    const int lane = tid & 63;
    const int wave = tid >> 6;

    // Ticket: virtual tile id in block-START order. For any running block, all
    // predecessors (lower tickets, same row) have already started => lookback
    // spin always terminates (they publish their aggregate before spinning).
    if (tid == 0) s_bid = atomicAdd(ticket, 1u);
    __syncthreads();
    const unsigned int bid = s_bid;
    const int row = (int)(bid >> 3);          // bid / GSEG
    const int g   = (int)(bid & (GSEG - 1));  // tile index within row

    const float4* p4 = (const float4*)(pred + (size_t)row * T_LEN + (size_t)g * TILE) + tid * 4;
    const float4* t4 = (const float4*)(tru  + (size_t)row * T_LEN + (size_t)g * TILE) + tid * 4;

    // Read tile ONCE into registers: 16 diffs/thread, contiguous per thread.
    float d[TPT];
    #pragma unroll
    for (int k = 0; k < 4; ++k) {
        float4 p = p4[k];
        float4 t = t4[k];
        d[4*k+0] = p.x - t.x;
        d[4*k+1] = p.y - t.y;
        d[4*k+2] = p.z - t.z;
        d[4*k+3] = p.w - t.w;
    }
    // thread-local inclusive prefix
    #pragma unroll
    for (int j = 1; j < TPT; ++j) d[j] += d[j-1];

    // wave-level inclusive scan of thread totals (one scan per block, not per chunk)
    float v = d[TPT-1];
    #pragma unroll
    for (int off = 1; off < 64; off <<= 1) {
        float u = __shfl_up(v, off, 64);
        if (lane >= off) v += u;
    }
    if (lane == 63) s_wtot[wave] = v;
    __syncthreads();

    float wprefix = 0.f, btot = 0.f;
    #pragma unroll
    for (int w = 0; w < 4; ++w) {
        float wt = s_wtot[w];
        if (w < wave) wprefix += wt;
        btot += wt;
    }
    const float texcl = wprefix + (v - d[TPT-1]);   // exclusive prefix within tile

    // Decoupled lookback (thread 0 only): publish aggregate first, then resolve carry.
    if (tid == 0) {
        float carry = 0.f;
        if (g == 0) {
            atomicExch(&slots[bid], pack_slot(2u, btot));
        } else {
            if (g != GSEG - 1)
                atomicExch(&slots[bid], pack_slot(1u, btot));   // aggregate visible early
            const unsigned int rbase = bid - (unsigned int)g;   // row's tile 0 slot
            int j = g - 1;
            for (;;) {
                unsigned long long s = atomicAdd(&slots[rbase + j], 0ULL); // atomic read
                unsigned int flag = (unsigned int)(s >> 32);
                if (flag == 0u) { __builtin_amdgcn_s_sleep(1); continue; }
                carry += __uint_as_float((unsigned int)s);
                if (flag == 2u || j == 0) break;
                --j;
            }
            if (g != GSEG - 1)
                atomicExch(&slots[bid], pack_slot(2u, carry + btot)); // upgrade to inclusive
        }
        s_carry = carry;
    }
    __syncthreads();

    // Weighted |cumsum| from registers: element e = g*TILE + tid*16 + j, weight T-e.
    const float excl = s_carry + texcl;
    const int   e0   = g * TILE + tid * TPT;
    const float w0   = (float)(T_LEN - e0);
    float part = 0.f;
    #pragma unroll
    for (int j = 0; j < TPT; ++j)
        part += fabsf(excl + d[j]) * (w0 - (float)j);

    // block reduction in double, then one device atomic per block
    double acc = (double)part;
    #pragma unroll
    for (int off = 32; off > 0; off >>= 1)
        acc += __shfl_down(acc, off, 64);
    if (lane == 0) s_dtot[wave] = acc;
    __syncthreads();

    if (tid == 0) {
        double sum = s_dtot[0] + s_dtot[1] + s_dtot[2] + s_dtot[3];
        atomicAdd(accum, sum);
        __threadfence();
        unsigned int done = atomicAdd(donecnt, 1u);
        if (done == NBLOCKS - 1) {          // last block finalizes: saves a dispatch
            __threadfence();
            double tot = atomicAdd(accum, 0.0);   // atomic read of final sum
            const double tc      = (double)T_LEN * (double)C_CH;      // 524288
            const double scaling = 2.0 / (tc * (tc + 1.0));
            out[0] = (float)(tot * scaling / (double)B_BATCH);
        }
    }
}

extern "C" void kernel_launch(void* const* d_in, const int* in_sizes, int n_in,
                              void* d_out, int out_size, void* d_ws, size_t ws_size,
                              hipStream_t stream)
{
    const float* pred = (const float*)d_in[0];
    const float* tru  = (const float*)d_in[1];

    // d_ws is re-poisoned to 0xAA before every launch -> zero flags/counters/accum
    hipMemsetAsync(d_ws, 0, WS_BYTES, stream);

    wloss_lookback_kernel<<<NBLOCKS, THREADS, 0, stream>>>(pred, tru, d_ws, (float*)d_out);
}

// Round 3
// 279.750 us; speedup vs baseline: 2.2953x; 2.2953x over previous
//
#include <hip/hip_runtime.h>

// Problem constants (fixed by setup_inputs: B=64, C=16, T=32768, fp32)
#define B_BATCH 64
#define C_CH    16
#define T_LEN   32768
#define THREADS 256
#define VEC     4
#define CHUNK   (THREADS * VEC)      // 1024 elements per chunk
#define NCHUNK  (T_LEN / CHUNK)      // 32 chunks per row
#define CPP     8                    // chunks per phase (staged in LDS together)
#define NPH     (NCHUNK / CPP)       // 4 phases per row
#define PHEL    (CPP * CHUNK)        // 8192 elements staged per phase (32 KB)
#define NROWS   (B_BATCH * C_CH)     // 1024 rows -> 1024 blocks (4 per CU)

// One block per row: NO inter-block communication, no atomics, no spin-waits.
// Carry crosses a dependency point only once per phase (4x per row) instead of
// once per chunk (32x in the old serial version); everything inside a phase is
// independent -> 16 hoistable float4 loads + 8 parallel shfl-scan chains.
__global__ __launch_bounds__(THREADS, 4) void wloss_scan_kernel(
    const float* __restrict__ pred,
    const float* __restrict__ tru,
    double* __restrict__ partials)
{
    __shared__ float  s_pref[PHEL];     // 32 KB: wave-local inclusive prefixes
    __shared__ float  s_wt[CPP * 4];    // per-(chunk,wave) totals -> exclusive carries
    __shared__ float  s_rowc;           // running row carry
    __shared__ double s_d[4];

    const int row  = blockIdx.x;
    const int tid  = threadIdx.x;
    const int lane = tid & 63;
    const int wave = tid >> 6;

    const float4* p4 = (const float4*)(pred + (size_t)row * T_LEN);
    const float4* t4 = (const float4*)(tru  + (size_t)row * T_LEN);

    if (tid == 0) s_rowc = 0.0f;
    double acc = 0.0;

    for (int ph = 0; ph < NPH; ++ph) {
        if (ph) __syncthreads();        // WAR: previous phase's LDS reads done

        // ---- stage 8 independent chunks into LDS ----
        #pragma unroll
        for (int c8 = 0; c8 < CPP; ++c8) {
            const int c   = ph * CPP + c8;
            const int idx = c * (CHUNK / VEC) + tid;   // coalesced float4
            float4 p = p4[idx];
            float4 t = t4[idx];
            float d0 = p.x - t.x, d1 = p.y - t.y, d2 = p.z - t.z, d3 = p.w - t.w;
            float s1 = d0, s2 = s1 + d1, s3 = s2 + d2, s4 = s3 + d3;

            float v = s4;                               // wave-inclusive scan
            #pragma unroll
            for (int off = 1; off < 64; off <<= 1) {
                float u = __shfl_up(v, off, 64);
                if (lane >= off) v += u;
            }
            const float we = v - s4;                    // in-wave exclusive prefix
            float4 st = { we + s1, we + s2, we + s3, we + s4 };
            *(float4*)&s_pref[c8 * CHUNK + tid * VEC] = st;   // contiguous 16B/lane
            if (lane == 63) s_wt[c8 * 4 + wave] = v;          // wave total
        }
        __syncthreads();

        // ---- resolve all 32 (chunk,wave) carries for this phase: one wave-scan ----
        if (wave == 0) {
            float val = (lane < 32) ? s_wt[lane] : 0.0f;
            float inc = val;
            #pragma unroll
            for (int off = 1; off < 32; off <<= 1) {
                float u = __shfl_up(inc, off, 64);
                if (lane >= off) inc += u;
            }
            const float rc = s_rowc;
            if (lane < 32) s_wt[lane] = rc + inc - val;   // exclusive carry per (chunk,wave)
            if (lane == 31) s_rowc = rc + inc;            // advance row carry
        }
        __syncthreads();

        // ---- weighted |cumsum| pass from LDS ----
        #pragma unroll
        for (int c8 = 0; c8 < CPP; ++c8) {
            const float carry = s_wt[c8 * 4 + wave];      // broadcast read, free
            float4 pr = *(const float4*)&s_pref[c8 * CHUNK + tid * VEC];
            const int   e0 = (ph * CPP + c8) * CHUNK + tid * VEC;
            const float w0 = (float)(T_LEN - e0);
            float part = fabsf(carry + pr.x) * w0
                       + fabsf(carry + pr.y) * (w0 - 1.0f)
                       + fabsf(carry + pr.z) * (w0 - 2.0f)
                       + fabsf(carry + pr.w) * (w0 - 3.0f);
            acc += (double)part;                          // same numerics as R0 (absmax 0.0)
        }
    }

    // block reduction of double acc: wave shuffle-reduce, then LDS across 4 waves
    #pragma unroll
    for (int off = 32; off > 0; off >>= 1)
        acc += __shfl_down(acc, off, 64);
    if (lane == 0) s_d[wave] = acc;
    __syncthreads();

    if (tid == 0)
        partials[row] = s_d[0] + s_d[1] + s_d[2] + s_d[3];   // plain store, no atomic
}

__global__ __launch_bounds__(THREADS) void wloss_finalize_kernel(
    const double* __restrict__ partials, float* __restrict__ out)
{
    const int tid  = threadIdx.x;
    const int lane = tid & 63;
    const int wave = tid >> 6;

    double acc = 0.0;
    for (int i = tid; i < NROWS; i += THREADS) acc += partials[i];

    #pragma unroll
    for (int off = 32; off > 0; off >>= 1)
        acc += __shfl_down(acc, off, 64);

    __shared__ double dtot[4];
    if (lane == 0) dtot[wave] = acc;
    __syncthreads();

    if (tid == 0) {
        const double tot     = dtot[0] + dtot[1] + dtot[2] + dtot[3];
        const double tc      = (double)T_LEN * (double)C_CH;      // 524288
        const double scaling = 2.0 / (tc * (tc + 1.0));
        out[0] = (float)(tot * scaling / (double)B_BATCH);
    }
}

extern "C" void kernel_launch(void* const* d_in, const int* in_sizes, int n_in,
                              void* d_out, int out_size, void* d_ws, size_t ws_size,
                              hipStream_t stream)
{
    const float* pred = (const float*)d_in[0];
    const float* tru  = (const float*)d_in[1];
    double*      partials = (double*)d_ws;    // 1024 doubles; fully overwritten
    float*       out      = (float*)d_out;

    // No workspace zeroing needed: every partial is written before finalize reads it.
    wloss_scan_kernel<<<NROWS, THREADS, 0, stream>>>(pred, tru, partials);
    wloss_finalize_kernel<<<1, THREADS, 0, stream>>>(partials, out);
}